// Round 18
// baseline (234.664 us; speedup 1.0000x reference)
//
#include <hip/hip_runtime.h>

typedef _Float16 half8 __attribute__((ext_vector_type(8)));
typedef float floatx4 __attribute__((ext_vector_type(4)));
typedef int intx4 __attribute__((ext_vector_type(4)));

#define MFMA16(a, b, c) __builtin_amdgcn_mfma_f32_16x16x32_f16(a, b, c, 0, 0, 0)

static __device__ __forceinline__ half8 asH8(intx4 v) {
  half8 r;
  __builtin_memcpy(&r, &v, 16);
  return r;
}

static constexpr int kD = 576;
// ws layout (f16 elements), kt-major for per-lane coalesced B loads:
//   WS1H: [kt:18][m:512][32]  hi   elem = kt*16384 + m*32 + (d&31)
//   WS1L: [kt:18][m:512][32]  lo   (+294912)
//   WS2T: [kt2:16][d:576][32] hi   elem = WS2T + kt2*18432 + d*32 + (m&31)
static constexpr int WS1L = 294912;
static constexpr int WS2T = 589824;
// total ws: 884736 f16 = 1,769,472 bytes

__global__ void prep_split(const float* __restrict__ mem, _Float16* __restrict__ ws) {
  const int m = blockIdx.x;   // 512
  const int d = threadIdx.x;  // 576
  float v = mem[m * kD + d];
  _Float16 hi = (_Float16)v;
  _Float16 lo = (_Float16)(v - (float)hi);
  const int kt = d >> 5;
  ws[kt * 16384 + m * 32 + (d & 31)] = hi;
  ws[WS1L + kt * 16384 + m * 32 + (d & 31)] = lo;
  ws[WS2T + (m >> 5) * 18432 + d * 32 + (m & 31)] = hi;
}

// per-lane 16B global load to VGPR; wave-coalesced (1KB contiguous per instr)
#define GLD16A(dst, base, voff)                              \
  asm volatile("global_load_dwordx4 %0, %1, %2 offset:0"     \
               : "=v"(dst)                                   \
               : "v"(voff), "s"(base))
#define VMW(N)                                            \
  do {                                                    \
    asm volatile("s_waitcnt vmcnt(" #N ")" ::: "memory"); \
    __builtin_amdgcn_sched_barrier(0);                    \
  } while (0)

// One block: 128 pixels = TWO (b,h) rows. 512 threads / 8 waves.
// Each B piece is loaded once and MFMA'd against both rows (2x amortization
// of the L2 B-traffic that bounds r11-r17). Wave-decoupled coalesced B loads
// into VGPR rings (G1 ring-3 VMW(8), G2 ring-4 VMW(15)), counted vmcnt,
// NO barriers inside GEMM loops.
__global__ __launch_bounds__(512, 2) void mem_branch_kernel(
    const float* __restrict__ x, const float* __restrict__ temperature,
    const _Float16* __restrict__ ws, float* __restrict__ out) {
  // blob (155648 B):
  //  [0,147456)        A-frags [2 rows][72][64][8] f16 (row stride 36864 elem)
  //                    -> att-frags [2 rows][64][64][8] (row stride 32768 elem)
  //  [147456,155648)   union{ tab[576] int (A-build only, pre-G1) |
  //                           redm[8][128]+reds[8][128] float (post-G1) }
  __shared__ __align__(16) unsigned char blob[155648];
  _Float16* afrag = (_Float16*)blob;
  int* tab = (int*)(blob + 147456);
  float* redm = (float*)(blob + 147456);
  float* reds = (float*)(blob + 147456 + 4096);

  const int tid = threadIdx.x;
  const int lane = tid & 63;
  const int wv = tid >> 6;  // 0..7
  const int l15 = lane & 15;
  const int koct = lane >> 4;  // 0..3
  const int bx = blockIdx.x;   // 512
  const int b = bx >> 5;
  const int h0 = (bx & 31) << 1;  // rows h0, h0+1

  const float sfac = temperature[0] * 0.060112293370373475f;  // (1/24)*log2(e)
  const _Float16* wsp = ws;
  const _Float16* wspl = ws + WS1L;
  const _Float16* wsp2 = ws + WS2T;

  for (int d = tid; d < kD; d += 512) {
    int c = d / 9, r9 = d % 9, kh = r9 / 3, kw = r9 % 3;
    tab[d] = (c << 12) + (kh << 6) + kw + (kh << 20) + (kw << 24);
  }
  __syncthreads();

  // ---- build A-hi fragments for BOTH rows in fragment layout ----
  {
    for (int i = 0; i < 18; ++i) {
      const int cc = i * 8 + wv;           // 0..143
      const int row = (cc >= 72) ? 1 : 0;  // which h-row
      const int combo = cc - (row ? 72 : 0);  // 0..71 = kt*4 + pt
      const int pt = combo & 3;
      const int kt = combo >> 2;
      const int pp = pt * 16 + l15;  // px = w
      const int hh = h0 + row;
      const int base0 = (b * 4096 + (hh - 1)) * 64 - 1;
      const int dbase = kt * 32 + koct * 8;
      intx4 t0 = *reinterpret_cast<const intx4*>(&tab[dbase]);
      intx4 t1 = *reinterpret_cast<const intx4*>(&tab[dbase + 4]);
      half8 hv;
#pragma unroll
      for (int j = 0; j < 8; ++j) {
        int t = (j < 4) ? t0[j] : t1[j - 4];
        int off = t & 0xFFFFF;
        int kh = (t >> 20) & 15;
        int kw = (t >> 24) & 15;
        bool ok = ((unsigned)(hh - 1 + kh) < 64u) && ((unsigned)(pp - 1 + kw) < 64u);
        int idx = ok ? (base0 + pp + off) : 0;
        float v = x[idx];
        v = ok ? v : 0.0f;
        hv[j] = (_Float16)v;
      }
      *reinterpret_cast<half8*>(&afrag[row * 36864 + combo * 512 + lane * 8]) = hv;
    }
  }
  __syncthreads();  // A-frags visible; tab dead -> redm/reds region free

  const _Float16* abase = afrag + lane * 8;

  // ---- GEMM1 (2-term hi*(hi+lo)): wave owns m in [wv*64,+64), 128 px ----
  // 36 half-kt pieces (4 coalesced loads each), ring-3 (U,V,W), issue 2 ahead.
  // Each piece: 32 MFMA (2 rows x 4 pt x 4 mt) on 4 B-regs.
  floatx4 acc[2][4][4];  // [row][pt][mt]
  const floatx4 zed = {0.0f, 0.0f, 0.0f, 0.0f};
#pragma unroll
  for (int r2 = 0; r2 < 2; ++r2)
#pragma unroll
    for (int pt = 0; pt < 4; ++pt)
#pragma unroll
      for (int mt = 0; mt < 4; ++mt) acc[r2][pt][mt] = zed;
  {
    int vb[4];
#pragma unroll
    for (int mt = 0; mt < 4; ++mt) vb[mt] = (wv * 64 + mt * 16 + l15) * 64 + koct * 16;
    intx4 U0, U1, U2, U3, V0, V1, V2, V3, W0, W1, W2, W3;
    half8 aA0, aA1, aA2, aA3, aB0, aB1, aB2, aB3;  // row0, row1 A-frags
    int aoff = 0;

#define G1_ISSUE(B, BASE, KIO)         \
  do {                                 \
    GLD16A(B##0, BASE, vb[0] + (KIO)); \
    GLD16A(B##1, BASE, vb[1] + (KIO)); \
    GLD16A(B##2, BASE, vb[2] + (KIO)); \
    GLD16A(B##3, BASE, vb[3] + (KIO)); \
  } while (0)

#define G1_AREAD                                                        \
  do {                                                                  \
    aA0 = *reinterpret_cast<const half8*>(abase + aoff);                \
    aA1 = *reinterpret_cast<const half8*>(abase + aoff + 512);          \
    aA2 = *reinterpret_cast<const half8*>(abase + aoff + 1024);         \
    aA3 = *reinterpret_cast<const half8*>(abase + aoff + 1536);         \
    aB0 = *reinterpret_cast<const half8*>(abase + 36864 + aoff);        \
    aB1 = *reinterpret_cast<const half8*>(abase + 36864 + aoff + 512);  \
    aB2 = *reinterpret_cast<const half8*>(abase + 36864 + aoff + 1024); \
    aB3 = *reinterpret_cast<const half8*>(abase + 36864 + aoff + 1536); \
    aoff += 2048;                                                       \
  } while (0)

#define G1_MMA(B)                                        \
  do {                                                   \
    __builtin_amdgcn_s_setprio(1);                       \
    acc[0][0][0] = MFMA16(aA0, asH8(B##0), acc[0][0][0]); \
    acc[0][1][0] = MFMA16(aA1, asH8(B##0), acc[0][1][0]); \
    acc[0][2][0] = MFMA16(aA2, asH8(B##0), acc[0][2][0]); \
    acc[0][3][0] = MFMA16(aA3, asH8(B##0), acc[0][3][0]); \
    acc[1][0][0] = MFMA16(aB0, asH8(B##0), acc[1][0][0]); \
    acc[1][1][0] = MFMA16(aB1, asH8(B##0), acc[1][1][0]); \
    acc[1][2][0] = MFMA16(aB2, asH8(B##0), acc[1][2][0]); \
    acc[1][3][0] = MFMA16(aB3, asH8(B##0), acc[1][3][0]); \
    acc[0][0][1] = MFMA16(aA0, asH8(B##1), acc[0][0][1]); \
    acc[0][1][1] = MFMA16(aA1, asH8(B##1), acc[0][1][1]); \
    acc[0][2][1] = MFMA16(aA2, asH8(B##1), acc[0][2][1]); \
    acc[0][3][1] = MFMA16(aA3, asH8(B##1), acc[0][3][1]); \
    acc[1][0][1] = MFMA16(aB0, asH8(B##1), acc[1][0][1]); \
    acc[1][1][1] = MFMA16(aB1, asH8(B##1), acc[1][1][1]); \
    acc[1][2][1] = MFMA16(aB2, asH8(B##1), acc[1][2][1]); \
    acc[1][3][1] = MFMA16(aB3, asH8(B##1), acc[1][3][1]); \
    acc[0][0][2] = MFMA16(aA0, asH8(B##2), acc[0][0][2]); \
    acc[0][1][2] = MFMA16(aA1, asH8(B##2), acc[0][1][2]); \
    acc[0][2][2] = MFMA16(aA2, asH8(B##2), acc[0][2][2]); \
    acc[0][3][2] = MFMA16(aA3, asH8(B##2), acc[0][3][2]); \
    acc[1][0][2] = MFMA16(aB0, asH8(B##2), acc[1][0][2]); \
    acc[1][1][2] = MFMA16(aB1, asH8(B##2), acc[1][1][2]); \
    acc[1][2][2] = MFMA16(aB2, asH8(B##2), acc[1][2][2]); \
    acc[1][3][2] = MFMA16(aB3, asH8(B##2), acc[1][3][2]); \
    acc[0][0][3] = MFMA16(aA0, asH8(B##3), acc[0][0][3]); \
    acc[0][1][3] = MFMA16(aA1, asH8(B##3), acc[0][1][3]); \
    acc[0][2][3] = MFMA16(aA2, asH8(B##3), acc[0][2][3]); \
    acc[0][3][3] = MFMA16(aA3, asH8(B##3), acc[0][3][3]); \
    acc[1][0][3] = MFMA16(aB0, asH8(B##3), acc[1][0][3]); \
    acc[1][1][3] = MFMA16(aB1, asH8(B##3), acc[1][1][3]); \
    acc[1][2][3] = MFMA16(aB2, asH8(B##3), acc[1][2][3]); \
    acc[1][3][3] = MFMA16(aB3, asH8(B##3), acc[1][3][3]); \
    __builtin_amdgcn_s_setprio(0);                       \
  } while (0)

    // pieces p: kt=p>>1, half=p&1 (0=hi,1=lo); ring = p%3; kio = (p>>1)*32768
    G1_ISSUE(U, wsp, 0);   // p0 hi kt0
    G1_ISSUE(V, wspl, 0);  // p1 lo kt0
    for (int g = 0; g < 5; ++g) {  // pieces 6g..6g+5, issues 6g+2..6g+7
      const int k1 = (3 * g + 1) * 32768, k2 = k1 + 32768, k3 = k2 + 32768;
      G1_ISSUE(W, wsp, k1);  G1_AREAD; VMW(8); G1_MMA(U);
      G1_ISSUE(U, wspl, k1);           VMW(8); G1_MMA(V);
      G1_ISSUE(V, wsp, k2);  G1_AREAD; VMW(8); G1_MMA(W);
      G1_ISSUE(W, wspl, k2);           VMW(8); G1_MMA(U);
      G1_ISSUE(U, wsp, k3);  G1_AREAD; VMW(8); G1_MMA(V);
      G1_ISSUE(V, wspl, k3);           VMW(8); G1_MMA(W);
    }
    // tail: pieces 30..35 (kt 15,16,17), issues 32..35 (kt 16,17)
    {
      const int k16 = 16 * 32768, k17 = 17 * 32768;
      G1_ISSUE(W, wsp, k16);  G1_AREAD; VMW(8); G1_MMA(U);  // p30 hi kt15
      G1_ISSUE(U, wspl, k16);           VMW(8); G1_MMA(V);  // p31 lo kt15
      G1_ISSUE(V, wsp, k17);  G1_AREAD; VMW(8); G1_MMA(W);  // p32 hi kt16
      G1_ISSUE(W, wspl, k17);           VMW(8); G1_MMA(U);  // p33 lo kt16
      G1_AREAD; VMW(4); G1_MMA(V);                          // p34 hi kt17
      VMW(0); G1_MMA(W);                                    // p35 lo kt17
    }
  }

  // ---- softmax over m=512 for both rows ----
  // lane: px = row*64 + pt*16 + koct*4 + r, m = wv*64 + mt*16 + l15
  float pm[2][4][4], ps[2][4][4];
#pragma unroll
  for (int r2 = 0; r2 < 2; ++r2)
#pragma unroll
    for (int pt = 0; pt < 4; ++pt)
#pragma unroll
      for (int r = 0; r < 4; ++r) {
        float v = acc[r2][pt][0][r];
#pragma unroll
        for (int mt = 1; mt < 4; ++mt) v = fmaxf(v, acc[r2][pt][mt][r]);
        pm[r2][pt][r] = v;
      }
#pragma unroll
  for (int off = 1; off < 16; off <<= 1)
#pragma unroll
    for (int r2 = 0; r2 < 2; ++r2)
#pragma unroll
      for (int pt = 0; pt < 4; ++pt)
#pragma unroll
        for (int r = 0; r < 4; ++r)
          pm[r2][pt][r] = fmaxf(pm[r2][pt][r], __shfl_xor(pm[r2][pt][r], off, 64));
  if (l15 == 0) {
#pragma unroll
    for (int r2 = 0; r2 < 2; ++r2)
#pragma unroll
      for (int pt = 0; pt < 4; ++pt)
#pragma unroll
        for (int r = 0; r < 4; ++r)
          redm[wv * 128 + r2 * 64 + pt * 16 + koct * 4 + r] = pm[r2][pt][r];
  }
  __syncthreads();
#pragma unroll
  for (int r2 = 0; r2 < 2; ++r2)
#pragma unroll
    for (int pt = 0; pt < 4; ++pt)
#pragma unroll
      for (int r = 0; r < 4; ++r) {
        const int p = r2 * 64 + pt * 16 + koct * 4 + r;
        float g = redm[p];
#pragma unroll
        for (int w = 1; w < 8; ++w) g = fmaxf(g, redm[w * 128 + p]);
        pm[r2][pt][r] = g;
        ps[r2][pt][r] = 0.0f;
      }
#pragma unroll
  for (int r2 = 0; r2 < 2; ++r2)
#pragma unroll
    for (int pt = 0; pt < 4; ++pt)
#pragma unroll
      for (int mt = 0; mt < 4; ++mt)
#pragma unroll
        for (int r = 0; r < 4; ++r) {
          float e = exp2f((acc[r2][pt][mt][r] - pm[r2][pt][r]) * sfac);
          acc[r2][pt][mt][r] = e;
          ps[r2][pt][r] += e;
        }
#pragma unroll
  for (int off = 1; off < 16; off <<= 1)
#pragma unroll
    for (int r2 = 0; r2 < 2; ++r2)
#pragma unroll
      for (int pt = 0; pt < 4; ++pt)
#pragma unroll
        for (int r = 0; r < 4; ++r) ps[r2][pt][r] += __shfl_xor(ps[r2][pt][r], off, 64);
  if (l15 == 0) {
#pragma unroll
    for (int r2 = 0; r2 < 2; ++r2)
#pragma unroll
      for (int pt = 0; pt < 4; ++pt)
#pragma unroll
        for (int r = 0; r < 4; ++r)
          reds[wv * 128 + r2 * 64 + pt * 16 + koct * 4 + r] = ps[r2][pt][r];
  }
  __syncthreads();
#pragma unroll
  for (int r2 = 0; r2 < 2; ++r2)
#pragma unroll
    for (int pt = 0; pt < 4; ++pt)
#pragma unroll
      for (int r = 0; r < 4; ++r) {
        const int p = r2 * 64 + pt * 16 + koct * 4 + r;
        float s = reds[p];
#pragma unroll
        for (int w = 1; w < 8; ++w) s += reds[w * 128 + p];
        ps[r2][pt][r] = 1.0f / s;
      }
  // write att-hi fragments into afrag: [row][kt2*4+pt][lane'][j']
#pragma unroll
  for (int r2 = 0; r2 < 2; ++r2)
#pragma unroll
    for (int pt = 0; pt < 4; ++pt)
#pragma unroll
      for (int mt = 0; mt < 4; ++mt)
#pragma unroll
        for (int r = 0; r < 4; ++r) {
          float a = acc[r2][pt][mt][r] * ps[r2][pt][r];
          const int m = wv * 64 + mt * 16 + l15;
          const int idxe = r2 * 32768 +
              (((m >> 5) * 4 + pt) * 64 + ((m >> 3) & 3) * 16 + koct * 4 + r) * 8 + (m & 7);
          afrag[idxe] = (_Float16)a;
        }
  __syncthreads();  // att-frags visible to all

  // ---- GEMM2 (hi-only): out[128][576] = att_hi @ mem_hi ----
  // wave owns 5 dtiles (pads clamped/skipped). 16 full-kt2 pieces (5 loads),
  // ring-4 (Ta..Td), issue 3 ahead. 40 MFMA/piece (2 rows x 5 nt x 4 pt).
  floatx4 acc2[2][5][4];  // [row][nt][pt]
#pragma unroll
  for (int r2 = 0; r2 < 2; ++r2)
#pragma unroll
    for (int nt = 0; nt < 5; ++nt)
#pragma unroll
      for (int pt = 0; pt < 4; ++pt) acc2[r2][nt][pt] = zed;
  {
    int vc[5];
#pragma unroll
    for (int nt = 0; nt < 5; ++nt) {
      int row = (wv * 5 + nt) * 16 + l15;
      if (row >= 576) row -= 576;  // pad rows clamp to valid data (discarded later)
      vc[nt] = row * 64 + koct * 16;
    }
    intx4 Ta0, Ta1, Ta2, Ta3, Ta4;
    intx4 Tb0, Tb1, Tb2, Tb3, Tb4;
    intx4 Tc0, Tc1, Tc2, Tc3, Tc4;
    intx4 Td0, Td1, Td2, Td3, Td4;
    half8 pA0, pA1, pA2, pA3, pB0, pB1, pB2, pB3;
    int aoff2 = 0;

#define G2_ISSUE(B, KIO)               \
  do {                                 \
    GLD16A(B##0, wsp2, vc[0] + (KIO)); \
    GLD16A(B##1, wsp2, vc[1] + (KIO)); \
    GLD16A(B##2, wsp2, vc[2] + (KIO)); \
    GLD16A(B##3, wsp2, vc[3] + (KIO)); \
    GLD16A(B##4, wsp2, vc[4] + (KIO)); \
  } while (0)

#define G2_AREAD                                                         \
  do {                                                                   \
    pA0 = *reinterpret_cast<const half8*>(abase + aoff2);                \
    pA1 = *reinterpret_cast<const half8*>(abase + aoff2 + 512);          \
    pA2 = *reinterpret_cast<const half8*>(abase + aoff2 + 1024);         \
    pA3 = *reinterpret_cast<const half8*>(abase + aoff2 + 1536);         \
    pB0 = *reinterpret_cast<const half8*>(abase + 32768 + aoff2);        \
    pB1 = *reinterpret_cast<const half8*>(abase + 32768 + aoff2 + 512);  \
    pB2 = *reinterpret_cast<const half8*>(abase + 32768 + aoff2 + 1024); \
    pB3 = *reinterpret_cast<const half8*>(abase + 32768 + aoff2 + 1536); \
    aoff2 += 2048;                                                       \
  } while (0)

#define G2_MMA(B)                                          \
  do {                                                     \
    __builtin_amdgcn_s_setprio(1);                         \
    acc2[0][0][0] = MFMA16(pA0, asH8(B##0), acc2[0][0][0]); \
    acc2[0][0][1] = MFMA16(pA1, asH8(B##0), acc2[0][0][1]); \
    acc2[0][0][2] = MFMA16(pA2, asH8(B##0), acc2[0][0][2]); \
    acc2[0][0][3] = MFMA16(pA3, asH8(B##0), acc2[0][0][3]); \
    acc2[1][0][0] = MFMA16(pB0, asH8(B##0), acc2[1][0][0]); \
    acc2[1][0][1] = MFMA16(pB1, asH8(B##0), acc2[1][0][1]); \
    acc2[1][0][2] = MFMA16(pB2, asH8(B##0), acc2[1][0][2]); \
    acc2[1][0][3] = MFMA16(pB3, asH8(B##0), acc2[1][0][3]); \
    acc2[0][1][0] = MFMA16(pA0, asH8(B##1), acc2[0][1][0]); \
    acc2[0][1][1] = MFMA16(pA1, asH8(B##1), acc2[0][1][1]); \
    acc2[0][1][2] = MFMA16(pA2, asH8(B##1), acc2[0][1][2]); \
    acc2[0][1][3] = MFMA16(pA3, asH8(B##1), acc2[0][1][3]); \
    acc2[1][1][0] = MFMA16(pB0, asH8(B##1), acc2[1][1][0]); \
    acc2[1][1][1] = MFMA16(pB1, asH8(B##1), acc2[1][1][1]); \
    acc2[1][1][2] = MFMA16(pB2, asH8(B##1), acc2[1][1][2]); \
    acc2[1][1][3] = MFMA16(pB3, asH8(B##1), acc2[1][1][3]); \
    acc2[0][2][0] = MFMA16(pA0, asH8(B##2), acc2[0][2][0]); \
    acc2[0][2][1] = MFMA16(pA1, asH8(B##2), acc2[0][2][1]); \
    acc2[0][2][2] = MFMA16(pA2, asH8(B##2), acc2[0][2][2]); \
    acc2[0][2][3] = MFMA16(pA3, asH8(B##2), acc2[0][2][3]); \
    acc2[1][2][0] = MFMA16(pB0, asH8(B##2), acc2[1][2][0]); \
    acc2[1][2][1] = MFMA16(pB1, asH8(B##2), acc2[1][2][1]); \
    acc2[1][2][2] = MFMA16(pB2, asH8(B##2), acc2[1][2][2]); \
    acc2[1][2][3] = MFMA16(pB3, asH8(B##2), acc2[1][2][3]); \
    acc2[0][3][0] = MFMA16(pA0, asH8(B##3), acc2[0][3][0]); \
    acc2[0][3][1] = MFMA16(pA1, asH8(B##3), acc2[0][3][1]); \
    acc2[0][3][2] = MFMA16(pA2, asH8(B##3), acc2[0][3][2]); \
    acc2[0][3][3] = MFMA16(pA3, asH8(B##3), acc2[0][3][3]); \
    acc2[1][3][0] = MFMA16(pB0, asH8(B##3), acc2[1][3][0]); \
    acc2[1][3][1] = MFMA16(pB1, asH8(B##3), acc2[1][3][1]); \
    acc2[1][3][2] = MFMA16(pB2, asH8(B##3), acc2[1][3][2]); \
    acc2[1][3][3] = MFMA16(pB3, asH8(B##3), acc2[1][3][3]); \
    acc2[0][4][0] = MFMA16(pA0, asH8(B##4), acc2[0][4][0]); \
    acc2[0][4][1] = MFMA16(pA1, asH8(B##4), acc2[0][4][1]); \
    acc2[0][4][2] = MFMA16(pA2, asH8(B##4), acc2[0][4][2]); \
    acc2[0][4][3] = MFMA16(pA3, asH8(B##4), acc2[0][4][3]); \
    acc2[1][4][0] = MFMA16(pB0, asH8(B##4), acc2[1][4][0]); \
    acc2[1][4][1] = MFMA16(pB1, asH8(B##4), acc2[1][4][1]); \
    acc2[1][4][2] = MFMA16(pB2, asH8(B##4), acc2[1][4][2]); \
    acc2[1][4][3] = MFMA16(pB3, asH8(B##4), acc2[1][4][3]); \
    __builtin_amdgcn_s_setprio(0);                         \
  } while (0)

    // pieces p: kt2 = p; ring = p%4; kio = p*36864
    G2_ISSUE(Ta, 0);
    G2_ISSUE(Tb, 36864);
    G2_ISSUE(Tc, 73728);
    for (int g = 0; g < 3; ++g) {  // pieces 4g..4g+3, issues 4g+3..4g+6
      const int j3 = (4 * g + 3) * 36864, j4 = j3 + 36864, j5 = j4 + 36864, j6 = j5 + 36864;
      G2_ISSUE(Td, j3); G2_AREAD; VMW(15); G2_MMA(Ta);
      G2_ISSUE(Ta, j4); G2_AREAD; VMW(15); G2_MMA(Tb);
      G2_ISSUE(Tb, j5); G2_AREAD; VMW(15); G2_MMA(Tc);
      G2_ISSUE(Tc, j6); G2_AREAD; VMW(15); G2_MMA(Td);
    }
    // tail: pieces 12..15, one remaining issue (15)
    G2_ISSUE(Td, 15 * 36864); G2_AREAD; VMW(15); G2_MMA(Ta);  // p12
    G2_AREAD; VMW(10); G2_MMA(Tb);                            // p13
    G2_AREAD; VMW(5);  G2_MMA(Tc);                            // p14
    G2_AREAD; VMW(0);  G2_MMA(Td);                            // p15
  }

  // ---- epilogue: nontemporal stores for both rows (skip pad tiles) ----
  {
    const int nbase = b * 4096 + h0 * 64;
#pragma unroll
    for (int r2 = 0; r2 < 2; ++r2)
#pragma unroll
      for (int nt = 0; nt < 5; ++nt) {
        const int dtile = wv * 5 + nt;
        if (dtile < 36) {
          const int d = dtile * 16 + l15;
#pragma unroll
          for (int pt = 0; pt < 4; ++pt)
#pragma unroll
            for (int r = 0; r < 4; ++r) {
              const int px = r2 * 64 + pt * 16 + koct * 4 + r;
              __builtin_nontemporal_store(acc2[r2][nt][pt][r], &out[(nbase + px) * 576 + d]);
            }
        }
      }
  }
}

extern "C" void kernel_launch(void* const* d_in, const int* in_sizes, int n_in,
                              void* d_out, int out_size, void* d_ws, size_t ws_size,
                              hipStream_t stream) {
  const float* x = (const float*)d_in[0];
  const float* memory = (const float*)d_in[1];
  const float* temperature = (const float*)d_in[2];
  float* out = (float*)d_out;
  _Float16* ws = (_Float16*)d_ws;  // needs 1,769,472 bytes

  prep_split<<<512, 576, 0, stream>>>(memory, ws);
  mem_branch_kernel<<<512, 512, 0, stream>>>(x, temperature, ws, out);
}

// Round 19
// 143.678 us; speedup vs baseline: 1.6333x; 1.6333x over previous
//
#include <hip/hip_runtime.h>

typedef _Float16 half8 __attribute__((ext_vector_type(8)));
typedef float floatx4 __attribute__((ext_vector_type(4)));
typedef int intx4 __attribute__((ext_vector_type(4)));

#define MFMA16(a, b, c) __builtin_amdgcn_mfma_f32_16x16x32_f16(a, b, c, 0, 0, 0)

static __device__ __forceinline__ half8 asH8(intx4 v) {
  half8 r;
  __builtin_memcpy(&r, &v, 16);
  return r;
}

static constexpr int kD = 576;
// ws layout (f16 elements), kt-major for per-lane coalesced B loads:
//   WS1H: [kt:18][m:512][32]  hi   elem = kt*16384 + m*32 + (d&31)
//   WS2T: [kt2:16][d:576][32] hi   elem = WS2T + kt2*18432 + d*32 + (m&31)
static constexpr int WS2T = 589824;
// total ws: 884736 f16 = 1,769,472 bytes (WS1L region now unused)

__global__ void prep_split(const float* __restrict__ mem, _Float16* __restrict__ ws) {
  const int m = blockIdx.x;   // 512
  const int d = threadIdx.x;  // 576
  float v = mem[m * kD + d];
  _Float16 hi = (_Float16)v;
  const int kt = d >> 5;
  ws[kt * 16384 + m * 32 + (d & 31)] = hi;
  ws[WS2T + (m >> 5) * 18432 + d * 32 + (m & 31)] = hi;
}

// per-lane 16B global load to VGPR; wave-coalesced (1KB contiguous per instr)
#define GLD16A(dst, base, voff)                              \
  asm volatile("global_load_dwordx4 %0, %1, %2 offset:0"     \
               : "=v"(dst)                                   \
               : "v"(voff), "s"(base))
#define VMW(N)                                            \
  do {                                                    \
    asm volatile("s_waitcnt vmcnt(" #N ")" ::: "memory"); \
    __builtin_amdgcn_sched_barrier(0);                    \
  } while (0)

// One block: 64 pixels = one (b,h) row. 512 threads / 8 waves.
// GEMM1 single-term (a_hi*b_hi): 18 full-kt pieces, ring-4, issue-ahead 3.
// GEMM2 single-term: 16 full-kt2 pieces, ring-4, issue-ahead 3.
// Wave-decoupled coalesced B loads into VGPR rings, counted vmcnt,
// NO barriers inside GEMM loops.
__global__ __launch_bounds__(512, 2) void mem_branch_kernel(
    const float* __restrict__ x, const float* __restrict__ temperature,
    const _Float16* __restrict__ ws, float* __restrict__ out) {
  // blob (77824 B):
  //  [0,73728)        A-frags (G1) -> att-frags (G2, 65536 used)
  //  [73728,77824)    union{ tab[576] int (A-build only, pre-G1) |
  //                          redm[512]+reds[512] float (softmax, post-G1) }
  __shared__ __align__(16) unsigned char blob[77824];
  _Float16* afrag = (_Float16*)blob;
  int* tab = (int*)(blob + 73728);
  float* redm = (float*)(blob + 73728);
  float* reds = (float*)(blob + 73728 + 2048);

  const int tid = threadIdx.x;
  const int lane = tid & 63;
  const int wv = tid >> 6;  // 0..7
  const int l15 = lane & 15;
  const int koct = lane >> 4;  // 0..3
  const int bx = blockIdx.x;   // 1024
  const int b = bx >> 6;
  const int h = bx & 63;

  const float sfac = temperature[0] * 0.060112293370373475f;  // (1/24)*log2(e)
  const _Float16* wsp = ws;
  const _Float16* wsp2 = ws + WS2T;

  for (int d = tid; d < kD; d += 512) {
    int c = d / 9, r9 = d % 9, kh = r9 / 3, kw = r9 % 3;
    tab[d] = (c << 12) + (kh << 6) + kw + (kh << 20) + (kw << 24);
  }
  __syncthreads();

  // ---- build A-hi fragments (64 px = full w row) in fragment layout ----
  {
    const int base0 = (b * 4096 + (h - 1)) * 64 - 1;
    for (int i = 0; i < 9; ++i) {
      const int combo = i * 8 + wv;  // 0..71 = kt*4 + pt
      const int pt = combo & 3;
      const int kt = combo >> 2;
      const int pp = pt * 16 + l15;  // px = w
      const int dbase = kt * 32 + koct * 8;
      intx4 t0 = *reinterpret_cast<const intx4*>(&tab[dbase]);
      intx4 t1 = *reinterpret_cast<const intx4*>(&tab[dbase + 4]);
      half8 hv;
#pragma unroll
      for (int j = 0; j < 8; ++j) {
        int t = (j < 4) ? t0[j] : t1[j - 4];
        int off = t & 0xFFFFF;
        int kh = (t >> 20) & 15;
        int kw = (t >> 24) & 15;
        bool ok = ((unsigned)(h - 1 + kh) < 64u) && ((unsigned)(pp - 1 + kw) < 64u);
        int idx = ok ? (base0 + pp + off) : 0;
        float v = x[idx];
        v = ok ? v : 0.0f;
        hv[j] = (_Float16)v;
      }
      *reinterpret_cast<half8*>(&afrag[combo * 512 + lane * 8]) = hv;
    }
  }
  __syncthreads();  // A-frags visible; tab dead -> redm/reds region free

  const _Float16* abase = afrag + lane * 8;

  // ---- GEMM1 (single-term a_hi*b_hi): wave owns m in [wv*64,+64), 64 px ----
  // 18 full-kt pieces (4 coalesced loads each), ring-4 (U,V,W,X), issue 3 ahead.
  floatx4 acc[4][4];  // [pt][mt]
  const floatx4 zed = {0.0f, 0.0f, 0.0f, 0.0f};
#pragma unroll
  for (int pt = 0; pt < 4; ++pt)
#pragma unroll
    for (int mt = 0; mt < 4; ++mt) acc[pt][mt] = zed;
  {
    int vb[4];
#pragma unroll
    for (int mt = 0; mt < 4; ++mt) vb[mt] = (wv * 64 + mt * 16 + l15) * 64 + koct * 16;
    intx4 U0, U1, U2, U3, V0, V1, V2, V3, W0, W1, W2, W3, X0, X1, X2, X3;
    half8 aa0, aa1, aa2, aa3;
    int aoff = 0;

#define G1_ISSUE(B, KIO)              \
  do {                                \
    GLD16A(B##0, wsp, vb[0] + (KIO)); \
    GLD16A(B##1, wsp, vb[1] + (KIO)); \
    GLD16A(B##2, wsp, vb[2] + (KIO)); \
    GLD16A(B##3, wsp, vb[3] + (KIO)); \
  } while (0)

#define G1_AREAD                                                \
  do {                                                          \
    aa0 = *reinterpret_cast<const half8*>(abase + aoff);        \
    aa1 = *reinterpret_cast<const half8*>(abase + aoff + 512);  \
    aa2 = *reinterpret_cast<const half8*>(abase + aoff + 1024); \
    aa3 = *reinterpret_cast<const half8*>(abase + aoff + 1536); \
    aoff += 2048;                                               \
  } while (0)

#define G1_MMA(B)                                   \
  do {                                              \
    __builtin_amdgcn_s_setprio(1);                  \
    acc[0][0] = MFMA16(aa0, asH8(B##0), acc[0][0]); \
    acc[1][0] = MFMA16(aa1, asH8(B##0), acc[1][0]); \
    acc[2][0] = MFMA16(aa2, asH8(B##0), acc[2][0]); \
    acc[3][0] = MFMA16(aa3, asH8(B##0), acc[3][0]); \
    acc[0][1] = MFMA16(aa0, asH8(B##1), acc[0][1]); \
    acc[1][1] = MFMA16(aa1, asH8(B##1), acc[1][1]); \
    acc[2][1] = MFMA16(aa2, asH8(B##1), acc[2][1]); \
    acc[3][1] = MFMA16(aa3, asH8(B##1), acc[3][1]); \
    acc[0][2] = MFMA16(aa0, asH8(B##2), acc[0][2]); \
    acc[1][2] = MFMA16(aa1, asH8(B##2), acc[1][2]); \
    acc[2][2] = MFMA16(aa2, asH8(B##2), acc[2][2]); \
    acc[3][2] = MFMA16(aa3, asH8(B##2), acc[3][2]); \
    acc[0][3] = MFMA16(aa0, asH8(B##3), acc[0][3]); \
    acc[1][3] = MFMA16(aa1, asH8(B##3), acc[1][3]); \
    acc[2][3] = MFMA16(aa2, asH8(B##3), acc[2][3]); \
    acc[3][3] = MFMA16(aa3, asH8(B##3), acc[3][3]); \
    __builtin_amdgcn_s_setprio(0);                  \
  } while (0)

    // pieces p = kt (0..17); ring = p%4; kio = p*32768. Prologue: p0,p1,p2.
    G1_ISSUE(U, 0);
    G1_ISSUE(V, 32768);
    G1_ISSUE(W, 65536);
    for (int g = 0; g < 3; ++g) {  // pieces 4g..4g+3, issues 4g+3..4g+6
      const int j3 = (4 * g + 3) * 32768;
      const int j4 = j3 + 32768, j5 = j4 + 32768, j6 = j5 + 32768;
      G1_ISSUE(X, j3); G1_AREAD; VMW(12); G1_MMA(U);
      G1_ISSUE(U, j4); G1_AREAD; VMW(12); G1_MMA(V);
      G1_ISSUE(V, j5); G1_AREAD; VMW(12); G1_MMA(W);
      G1_ISSUE(W, j6); G1_AREAD; VMW(12); G1_MMA(X);
    }
    // tail: pieces 12..17, remaining issues p15,p16,p17
    G1_ISSUE(X, 15 * 32768); G1_AREAD; VMW(12); G1_MMA(U);  // p12
    G1_ISSUE(U, 16 * 32768); G1_AREAD; VMW(12); G1_MMA(V);  // p13
    G1_ISSUE(V, 17 * 32768); G1_AREAD; VMW(12); G1_MMA(W);  // p14
    G1_AREAD; VMW(8); G1_MMA(X);                            // p15
    G1_AREAD; VMW(4); G1_MMA(U);                            // p16
    G1_AREAD; VMW(0); G1_MMA(V);                            // p17
  }

  // ---- softmax over m=512; lane: px = pt*16+koct*4+r, m = wv*64+mt*16+l15 ----
  float pm[4][4], ps[4][4];
#pragma unroll
  for (int pt = 0; pt < 4; ++pt)
#pragma unroll
    for (int r = 0; r < 4; ++r) {
      float v = acc[pt][0][r];
#pragma unroll
      for (int mt = 1; mt < 4; ++mt) v = fmaxf(v, acc[pt][mt][r]);
      pm[pt][r] = v;
    }
#pragma unroll
  for (int off = 1; off < 16; off <<= 1)
#pragma unroll
    for (int pt = 0; pt < 4; ++pt)
#pragma unroll
      for (int r = 0; r < 4; ++r) pm[pt][r] = fmaxf(pm[pt][r], __shfl_xor(pm[pt][r], off, 64));
  if (l15 == 0) {
#pragma unroll
    for (int pt = 0; pt < 4; ++pt)
#pragma unroll
      for (int r = 0; r < 4; ++r) redm[wv * 64 + pt * 16 + koct * 4 + r] = pm[pt][r];
  }
  __syncthreads();
#pragma unroll
  for (int pt = 0; pt < 4; ++pt)
#pragma unroll
    for (int r = 0; r < 4; ++r) {
      const int p = pt * 16 + koct * 4 + r;
      float g = redm[p];
#pragma unroll
      for (int w = 1; w < 8; ++w) g = fmaxf(g, redm[w * 64 + p]);
      pm[pt][r] = g;
      ps[pt][r] = 0.0f;
    }
#pragma unroll
  for (int pt = 0; pt < 4; ++pt)
#pragma unroll
    for (int mt = 0; mt < 4; ++mt)
#pragma unroll
      for (int r = 0; r < 4; ++r) {
        float e = exp2f((acc[pt][mt][r] - pm[pt][r]) * sfac);
        acc[pt][mt][r] = e;
        ps[pt][r] += e;
      }
#pragma unroll
  for (int off = 1; off < 16; off <<= 1)
#pragma unroll
    for (int pt = 0; pt < 4; ++pt)
#pragma unroll
      for (int r = 0; r < 4; ++r) ps[pt][r] += __shfl_xor(ps[pt][r], off, 64);
  if (l15 == 0) {
#pragma unroll
    for (int pt = 0; pt < 4; ++pt)
#pragma unroll
      for (int r = 0; r < 4; ++r) reds[wv * 64 + pt * 16 + koct * 4 + r] = ps[pt][r];
  }
  __syncthreads();
#pragma unroll
  for (int pt = 0; pt < 4; ++pt)
#pragma unroll
    for (int r = 0; r < 4; ++r) {
      const int p = pt * 16 + koct * 4 + r;
      float s = reds[p];
#pragma unroll
      for (int w = 1; w < 8; ++w) s += reds[w * 64 + p];
      ps[pt][r] = 1.0f / s;
    }
  // write att-hi fragments into afrag (A-frags dead: all waves past G1 via sync)
#pragma unroll
  for (int pt = 0; pt < 4; ++pt)
#pragma unroll
    for (int mt = 0; mt < 4; ++mt)
#pragma unroll
      for (int r = 0; r < 4; ++r) {
        float a = acc[pt][mt][r] * ps[pt][r];
        const int m = wv * 64 + mt * 16 + l15;
        const int idxe =
            (((m >> 5) * 4 + pt) * 64 + ((m >> 3) & 3) * 16 + koct * 4 + r) * 8 + (m & 7);
        afrag[idxe] = (_Float16)a;
      }
  __syncthreads();  // att-frags visible to all

  // ---- GEMM2 (hi-only): out[64][576] = att_hi @ mem_hi ----
  // wave owns 5 dtiles wv*5..wv*5+4 (tiles >=36 pad: clamped src, stores skipped).
  // 16 full-kt2 pieces (5 coalesced loads), ring-4 (Ta..Td), issue 3 ahead.
  floatx4 acc2[5][4];  // [nt][pt]
#pragma unroll
  for (int nt = 0; nt < 5; ++nt)
#pragma unroll
    for (int pt = 0; pt < 4; ++pt) acc2[nt][pt] = zed;
  {
    int vc[5];
#pragma unroll
    for (int nt = 0; nt < 5; ++nt) {
      int row = (wv * 5 + nt) * 16 + l15;
      if (row >= 576) row -= 576;  // pad rows clamp to valid data (discarded later)
      vc[nt] = row * 64 + koct * 16;
    }
    intx4 Ta0, Ta1, Ta2, Ta3, Ta4;
    intx4 Tb0, Tb1, Tb2, Tb3, Tb4;
    intx4 Tc0, Tc1, Tc2, Tc3, Tc4;
    intx4 Td0, Td1, Td2, Td3, Td4;
    half8 p0, p1, p2, p3;
    int aoff2 = 0;

#define G2_ISSUE(B, KIO)               \
  do {                                 \
    GLD16A(B##0, wsp2, vc[0] + (KIO)); \
    GLD16A(B##1, wsp2, vc[1] + (KIO)); \
    GLD16A(B##2, wsp2, vc[2] + (KIO)); \
    GLD16A(B##3, wsp2, vc[3] + (KIO)); \
    GLD16A(B##4, wsp2, vc[4] + (KIO)); \
  } while (0)

#define G2_AREAD                                                \
  do {                                                          \
    p0 = *reinterpret_cast<const half8*>(abase + aoff2);        \
    p1 = *reinterpret_cast<const half8*>(abase + aoff2 + 512);  \
    p2 = *reinterpret_cast<const half8*>(abase + aoff2 + 1024); \
    p3 = *reinterpret_cast<const half8*>(abase + aoff2 + 1536); \
    aoff2 += 2048;                                              \
  } while (0)

#define G2_MMA(B)                                    \
  do {                                               \
    __builtin_amdgcn_s_setprio(1);                   \
    acc2[0][0] = MFMA16(p0, asH8(B##0), acc2[0][0]); \
    acc2[0][1] = MFMA16(p1, asH8(B##0), acc2[0][1]); \
    acc2[0][2] = MFMA16(p2, asH8(B##0), acc2[0][2]); \
    acc2[0][3] = MFMA16(p3, asH8(B##0), acc2[0][3]); \
    acc2[1][0] = MFMA16(p0, asH8(B##1), acc2[1][0]); \
    acc2[1][1] = MFMA16(p1, asH8(B##1), acc2[1][1]); \
    acc2[1][2] = MFMA16(p2, asH8(B##1), acc2[1][2]); \
    acc2[1][3] = MFMA16(p3, asH8(B##1), acc2[1][3]); \
    acc2[2][0] = MFMA16(p0, asH8(B##2), acc2[2][0]); \
    acc2[2][1] = MFMA16(p1, asH8(B##2), acc2[2][1]); \
    acc2[2][2] = MFMA16(p2, asH8(B##2), acc2[2][2]); \
    acc2[2][3] = MFMA16(p3, asH8(B##2), acc2[2][3]); \
    acc2[3][0] = MFMA16(p0, asH8(B##3), acc2[3][0]); \
    acc2[3][1] = MFMA16(p1, asH8(B##3), acc2[3][1]); \
    acc2[3][2] = MFMA16(p2, asH8(B##3), acc2[3][2]); \
    acc2[3][3] = MFMA16(p3, asH8(B##3), acc2[3][3]); \
    acc2[4][0] = MFMA16(p0, asH8(B##4), acc2[4][0]); \
    acc2[4][1] = MFMA16(p1, asH8(B##4), acc2[4][1]); \
    acc2[4][2] = MFMA16(p2, asH8(B##4), acc2[4][2]); \
    acc2[4][3] = MFMA16(p3, asH8(B##4), acc2[4][3]); \
    __builtin_amdgcn_s_setprio(0);                   \
  } while (0)

    // pieces p: kt2 = p; ring = p%4; kio = p*36864
    G2_ISSUE(Ta, 0);
    G2_ISSUE(Tb, 36864);
    G2_ISSUE(Tc, 73728);
    for (int g = 0; g < 3; ++g) {  // pieces 4g..4g+3, issues 4g+3..4g+6
      const int j3 = (4 * g + 3) * 36864, j4 = j3 + 36864, j5 = j4 + 36864, j6 = j5 + 36864;
      G2_ISSUE(Td, j3); G2_AREAD; VMW(15); G2_MMA(Ta);
      G2_ISSUE(Ta, j4); G2_AREAD; VMW(15); G2_MMA(Tb);
      G2_ISSUE(Tb, j5); G2_AREAD; VMW(15); G2_MMA(Tc);
      G2_ISSUE(Tc, j6); G2_AREAD; VMW(15); G2_MMA(Td);
    }
    // tail: pieces 12..15, one remaining issue (15)
    G2_ISSUE(Td, 15 * 36864); G2_AREAD; VMW(15); G2_MMA(Ta);  // p12
    G2_AREAD; VMW(10); G2_MMA(Tb);                            // p13
    G2_AREAD; VMW(5);  G2_MMA(Tc);                            // p14
    G2_AREAD; VMW(0);  G2_MMA(Td);                            // p15
  }

  // ---- epilogue: nontemporal stores (skip pad tiles) ----
  {
    const int nbase = b * 4096 + h * 64;
#pragma unroll
    for (int nt = 0; nt < 5; ++nt) {
      const int dtile = wv * 5 + nt;
      if (dtile < 36) {
        const int d = dtile * 16 + l15;
#pragma unroll
        for (int pt = 0; pt < 4; ++pt)
#pragma unroll
          for (int r = 0; r < 4; ++r) {
            const int px = pt * 16 + koct * 4 + r;
            __builtin_nontemporal_store(acc2[nt][pt][r], &out[(nbase + px) * 576 + d]);
          }
      }
    }
  }
}

extern "C" void kernel_launch(void* const* d_in, const int* in_sizes, int n_in,
                              void* d_out, int out_size, void* d_ws, size_t ws_size,
                              hipStream_t stream) {
  const float* x = (const float*)d_in[0];
  const float* memory = (const float*)d_in[1];
  const float* temperature = (const float*)d_in[2];
  float* out = (float*)d_out;
  _Float16* ws = (_Float16*)d_ws;  // needs 1,769,472 bytes

  prep_split<<<512, 576, 0, stream>>>(memory, ws);
  mem_branch_kernel<<<1024, 512, 0, stream>>>(x, temperature, ws, out);
}